// Round 3
// baseline (83.964 us; speedup 1.0000x reference)
//
#include <hip/hip_runtime.h>

// Problem constants: B=4, K=8, H=W=64 -> N=4096, D=64, codes are 8-bit.
#define BATCH  4
#define KBITS  8
#define NPOS   4096
#define DDIM   64
#define NCODES 256

// ---------------------------------------------------------------------------
// K1: 16 blocks per batch (grid=64), 256 threads, one position per thread.
// Coalesced scalar plane loads (64 lanes x 4B = full 256B transactions),
// LDS histogram of evidence codes, then NON-ATOMIC partial store to
// hist_part[block][256] (no memset, no global atomics).
// ---------------------------------------------------------------------------
__global__ void k_codes_hist(const float* __restrict__ z,
                             const int* __restrict__ evidence_mask,
                             unsigned char* __restrict__ codes,
                             int* __restrict__ hist_part) {
    const int b  = blockIdx.x >> 4;
    const int n  = (blockIdx.x & 15) * 256 + threadIdx.x;
    const int tid = threadIdx.x;

    __shared__ int h[NCODES];
    h[tid] = 0;
    __syncthreads();

    const float* zb = z + (size_t)b * KBITS * NPOS;
    int code = 0;
#pragma unroll
    for (int k = 0; k < KBITS; ++k)
        code |= (int)(zb[k * NPOS + n] > 0.5f) << k;
    codes[b * NPOS + n] = (unsigned char)code;
    if (evidence_mask[b * NPOS + n] != 0) atomicAdd(&h[code], 1);
    __syncthreads();
    hist_part[blockIdx.x * NCODES + tid] = h[tid];   // coalesced, non-atomic
}

// ---------------------------------------------------------------------------
// K2: butterfly table build. One block per batch, 1024 threads.
//
// M[cq][c] = r^pop(cq^c), r = exp(-1/t), is the 8-fold Kronecker product
// of [[1,r],[r,1]] = (I + r*X). Hence rowg = M*(cnt .* VT) and den = M*cnt
// via 8 butterfly stages: G'[c] = G[c] + r*G[c ^ (1<<k)]. The global e^{mn/t}
// stabilizer of the reference cancels in the num/den ratio. 262K FMA/batch
// replaces 4.2M FMA + 65K exp of the per-query-dot formulation.
//
// Thread map: wave w (0..15), lane l (0..63): d = (w<<2)|(l>>4), thread owns
// c = (l&15)|(i<<4) for i = 0..15 (16 regs). c-bits 4..7 -> in-register
// butterfly (static unrolled indices); c-bits 0..3 -> __shfl_xor (partner
// l^m keeps d unchanged since d depends only on l>>4).
//
// All-masked batch: cnt==0 everywhere -> den==0 -> 1e-20 floor -> rowg 0
// (matches ref). mask_value never contributes (attn==0 off-evidence).
// ---------------------------------------------------------------------------
__global__ __launch_bounds__(1024)
void k_butterfly(const int* __restrict__ hist_part,
                 const float* __restrict__ value_table,
                 const float* __restrict__ temperature,
                 float* __restrict__ rowg) {
    const int b   = blockIdx.x;
    const int tid = threadIdx.x;

    __shared__ float cnt_sh[NCODES];
    if (tid < NCODES) {
        int s = 0;
#pragma unroll
        for (int j = 0; j < 16; ++j)
            s += hist_part[(b * 16 + j) * NCODES + tid];
        cnt_sh[tid] = (float)s;
    }
    __syncthreads();

    const int l   = tid & 63;
    const int w   = tid >> 6;
    const int d   = (w << 2) | (l >> 4);
    const int clo = l & 15;
    const float r = __expf(-1.0f / fmaxf(temperature[0], 0.1f));

    float g[16], nn[16];
#pragma unroll
    for (int i = 0; i < 16; ++i) {
        const int c  = clo | (i << 4);
        const float cf = cnt_sh[c];
        nn[i] = cf;
        g[i]  = cf * value_table[(c << 6) | d];
    }

    // c-bits 4..7: intra-thread butterfly (compile-time indices -> registers)
#pragma unroll
    for (int k = 0; k < 4; ++k) {
        const int m = 1 << k;
#pragma unroll
        for (int i = 0; i < 16; ++i) {
            if ((i & m) == 0) {
                const int j = i | m;
                const float a = g[i],  bb = g[j];
                g[i]  = fmaf(r, bb, a);  g[j]  = fmaf(r, a, bb);
                const float na = nn[i], nb = nn[j];
                nn[i] = fmaf(r, nb, na); nn[j] = fmaf(r, na, nb);
            }
        }
    }
    // c-bits 0..3: cross-lane butterfly (shfl returns pre-update values)
#pragma unroll
    for (int k = 0; k < 4; ++k) {
        const int m = 1 << k;
#pragma unroll
        for (int i = 0; i < 16; ++i) {
            const float o  = __shfl_xor(g[i],  m);
            g[i]  = fmaf(r, o, g[i]);
            const float on = __shfl_xor(nn[i], m);
            nn[i] = fmaf(r, on, nn[i]);
        }
    }

    // pre-divided table store: rowg[b][c][d] = num/den
    float* rb = rowg + ((size_t)b << 14);
#pragma unroll
    for (int i = 0; i < 16; ++i) {
        const int c = clo | (i << 4);
        rb[(c << 6) | d] = g[i] / fmaxf(nn[i], 1e-20f);
    }
}

// ---------------------------------------------------------------------------
// K3: gather. out (B, D, N): out[(b*D+d)*N + n] = rowg[b][codes[b][n]][d]
// 4 elements per thread: uchar4 code load, float4 store. Table is 64 KB
// per batch -> L1/L2 resident.
// ---------------------------------------------------------------------------
__global__ void k_gather(const unsigned char* __restrict__ codes,
                         const float* __restrict__ rowg,
                         float* __restrict__ out) {
    const int gid  = blockIdx.x * 256 + threadIdx.x;   // < 262144
    const int base = gid * 4;                          // element index
    const int n4   = base & (NPOS - 1);                // multiple of 4
    const int bd   = base >> 12;                       // NPOS = 2^12
    const int d    = bd & (DDIM - 1);
    const int b    = bd >> 6;

    const uchar4 c4 = *(const uchar4*)(codes + b * NPOS + n4);
    const float* rb = rowg + ((size_t)b << 14) + d;
    float4 o;
    o.x = rb[(int)c4.x << 6];
    o.y = rb[(int)c4.y << 6];
    o.z = rb[(int)c4.z << 6];
    o.w = rb[(int)c4.w << 6];
    *(float4*)(out + base) = o;
}

extern "C" void kernel_launch(void* const* d_in, const int* in_sizes, int n_in,
                              void* d_out, int out_size, void* d_ws, size_t ws_size,
                              hipStream_t stream) {
    const float* z           = (const float*)d_in[0];  // (B,K,H,W) fp32
    const int*   evidence    = (const int*)d_in[1];    // (B,N) bool->int32
    const float* temperature = (const float*)d_in[2];  // scalar
    const float* value_table = (const float*)d_in[3];  // (256,D) fp32
    // d_in[4] mask_value: never contributes (attn==0 off-evidence)
    // d_in[5] pop_lut: replaced by __popc

    float* out = (float*)d_out;  // (B,D,H,W) fp32

    unsigned char* codes     = (unsigned char*)d_ws;                  // 16 KB
    int*           hist_part = (int*)((char*)d_ws + 16384);           // 64 KB
    float*         rowg      = (float*)((char*)d_ws + 16384 + 65536); // 256 KB

    k_codes_hist<<<BATCH * 16, 256, 0, stream>>>(z, evidence, codes, hist_part);
    k_butterfly<<<BATCH, 1024, 0, stream>>>(hist_part, value_table, temperature, rowg);
    k_gather<<<(BATCH * DDIM * NPOS) / (256 * 4), 256, 0, stream>>>(codes, rowg, out);
}